// Round 8
// baseline (1616.511 us; speedup 1.0000x reference)
//
#include <hip/hip_runtime.h>

#define NN 150000
#define NP 150016   // NN padded to multiple of 128
#define NE 600000
#define NG 8192
#define DD 128
#define FINN 16
#define NL 4
#define NEL 500000
#define BN_EPS 1e-5f
#define NB_SCAN 147  // ceil(NN/1024)

typedef __attribute__((ext_vector_type(8))) short bf16x8;
typedef __attribute__((ext_vector_type(4))) float f32x4;

__device__ inline short bfr(float x) {
    unsigned u = __builtin_bit_cast(unsigned, x);
    unsigned r = u + 0x7fffu + ((u >> 16) & 1u);
    return (short)(r >> 16);
}
__device__ inline float bf2f(short h) {
    return __builtin_bit_cast(float, ((unsigned)(unsigned short)h) << 16);
}

// ---------------- encoder: A[n][d] = x[n][:16] @ encW + encb ----------------
__global__ __launch_bounds__(256) void enc_kernel(const float* __restrict__ x,
                                                  const float* __restrict__ W,
                                                  const float* __restrict__ b,
                                                  float* __restrict__ out) {
    int t = threadIdx.x;
    int c4 = (t & 31) * 4;
    float4 wreg[16];
#pragma unroll
    for (int k = 0; k < 16; k++) wreg[k] = *(const float4*)&W[k * DD + c4];
    float4 bias = *(const float4*)&b[c4];
    int rbase = blockIdx.x * 128 + (t >> 5);
#pragma unroll
    for (int it = 0; it < 16; it++) {
        int row = rbase + it * 8;
        if (row >= NN) break;
        const float4* xr = (const float4*)(x + (size_t)row * FINN);
        float4 x0 = xr[0], x1 = xr[1], x2 = xr[2], x3 = xr[3];
        float xs[16] = {x0.x, x0.y, x0.z, x0.w, x1.x, x1.y, x1.z, x1.w,
                        x2.x, x2.y, x2.z, x2.w, x3.x, x3.y, x3.z, x3.w};
        float4 acc = bias;
#pragma unroll
        for (int k = 0; k < 16; k++) {
            acc.x += xs[k] * wreg[k].x;
            acc.y += xs[k] * wreg[k].y;
            acc.z += xs[k] * wreg[k].z;
            acc.w += xs[k] * wreg[k].w;
        }
        *(float4*)&out[(size_t)row * DD + c4] = acc;
    }
}

// ------- pack 9 weight matrices into MFMA B-fragment layout, hi+lo split -------
__global__ void prep_w_kernel(const float* __restrict__ initW, const float* __restrict__ W1,
                              const float* __restrict__ W2, bf16x8* __restrict__ Wph,
                              bf16x8* __restrict__ Wpl) {
    int tid = blockIdx.x * 256 + threadIdx.x;  // 9*2048 = 18432
    if (tid >= 9 * 2048) return;
    int mat = tid >> 11;
    int rem = tid & 2047;
    int kk = rem >> 9;
    int c = (rem >> 6) & 7;
    int lane = rem & 63;
    const float* Wm;
    if (mat == 0) Wm = initW;
    else if (mat <= 4) Wm = W1 + (size_t)(mat - 1) * DD * DD;
    else Wm = W2 + (size_t)(mat - 5) * DD * DD;
    int col = c * 16 + (lane & 15);
    int kbase = kk * 32 + (lane >> 4) * 8;
    bf16x8 oh, ol;
#pragma unroll
    for (int j = 0; j < 8; j++) {
        float v = Wm[(size_t)(kbase + j) * DD + col];
        short h = bfr(v);
        oh[j] = h;
        ol[j] = bfr(v - bf2f(h));
    }
    Wph[tid] = oh;
    Wpl[tid] = ol;
}

// ---------------- fold BN into per-column scale/bias ----------------
__global__ void prep_scb_kernel(const float* __restrict__ initb,
                                const float* __restrict__ b1, const float* __restrict__ g1,
                                const float* __restrict__ be1, const float* __restrict__ rm1,
                                const float* __restrict__ rv1,
                                const float* __restrict__ b2, const float* __restrict__ g2,
                                const float* __restrict__ be2, const float* __restrict__ rm2,
                                const float* __restrict__ rv2,
                                float* __restrict__ sc, float* __restrict__ bb) {
    int tid = blockIdx.x * 256 + threadIdx.x;  // 9*128
    if (tid >= 9 * DD) return;
    int mat = tid >> 7, d = tid & 127;
    float s, o;
    if (mat == 0) {
        s = 1.f;
        o = initb[d];
    } else {
        const float *b_, *g_, *be_, *rm_, *rv_;
        int i;
        if (mat <= 4) { i = mat - 1; b_ = b1; g_ = g1; be_ = be1; rm_ = rm1; rv_ = rv1; }
        else          { i = mat - 5; b_ = b2; g_ = g2; be_ = be2; rm_ = rm2; rv_ = rv2; }
        float t = g_[i * DD + d] * rsqrtf(rv_[i * DD + d] + BN_EPS);
        s = t;
        o = (b_[i * DD + d] - rm_[i * DD + d]) * t + be_[i * DD + d];
    }
    sc[tid] = s;
    bb[tid] = o;
}

// ---------------- CSR build ----------------
__global__ void zero_int_kernel(int* __restrict__ p, int n) {
    int i = blockIdx.x * 256 + threadIdx.x;
    if (i < n) p[i] = 0;
}

__global__ void zero_f4_kernel(float4* __restrict__ p, int n4) {
    int i = blockIdx.x * 256 + threadIdx.x;
    if (i < n4) p[i] = make_float4(0.f, 0.f, 0.f, 0.f);
}

__global__ void hist_kernel(const int* __restrict__ dst, int* __restrict__ deg) {
    int e = blockIdx.x * 256 + threadIdx.x;
    if (e < NE) atomicAdd(&deg[dst[e]], 1);
}

__global__ void scan_reduce_kernel(const int* __restrict__ deg, int* __restrict__ bsum) {
    __shared__ int s[256];
    int b = blockIdx.x, t = threadIdx.x;
    int base = b * 1024 + t * 4;
    int v = 0;
#pragma unroll
    for (int i = 0; i < 4; i++) {
        int idx = base + i;
        if (idx < NN) v += deg[idx];
    }
    s[t] = v;
    __syncthreads();
    for (int off = 128; off > 0; off >>= 1) {
        if (t < off) s[t] += s[t + off];
        __syncthreads();
    }
    if (t == 0) bsum[b] = s[0];
}

__global__ void scan_mid_kernel(const int* __restrict__ bsum, int* __restrict__ boff,
                                int* __restrict__ rowptrN) {
    __shared__ int s[256];
    int t = threadIdx.x;
    int v = (t < NB_SCAN) ? bsum[t] : 0;
    s[t] = v;
    __syncthreads();
    for (int off = 1; off < 256; off <<= 1) {
        int u = (t >= off) ? s[t - off] : 0;
        __syncthreads();
        s[t] += u;
        __syncthreads();
    }
    if (t < NB_SCAN) boff[t] = s[t] - v;
    if (t == 255) *rowptrN = s[255];
}

__global__ void scan_final_kernel(const int* __restrict__ deg, const int* __restrict__ boff,
                                  int* __restrict__ rowptr) {
    __shared__ int s[256];
    int b = blockIdx.x, t = threadIdx.x;
    int base = b * 1024 + t * 4;
    int v[4];
    int sum = 0;
#pragma unroll
    for (int i = 0; i < 4; i++) {
        int idx = base + i;
        v[i] = (idx < NN) ? deg[idx] : 0;
        sum += v[i];
    }
    s[t] = sum;
    __syncthreads();
    int my = sum;
    for (int off = 1; off < 256; off <<= 1) {
        int u = (t >= off) ? s[t - off] : 0;
        __syncthreads();
        s[t] += u;
        __syncthreads();
    }
    int excl = s[t] - my + boff[b];
#pragma unroll
    for (int i = 0; i < 4; i++) {
        int idx = base + i;
        if (idx < NN) rowptr[idx] = excl;
        excl += v[i];
    }
}

__global__ void copy_int_kernel(const int* __restrict__ a, int* __restrict__ b, int n) {
    int i = blockIdx.x * 256 + threadIdx.x;
    if (i < n) b[i] = a[i];
}

__global__ void fill_kernel(const int* __restrict__ src, const int* __restrict__ dst,
                            int* cursor, int* __restrict__ csr_src) {
    int e = blockIdx.x * 256 + threadIdx.x;
    if (e >= NE) return;
    int p = atomicAdd(&cursor[dst[e]], 1);
    csr_src[p] = src[e];
}

// ---------------- graph segment starts (batch sorted) ----------------
__global__ void gstart_kernel(const int* __restrict__ batch, int* __restrict__ gstart) {
    int n = blockIdx.x * 256 + threadIdx.x;
    if (n >= NN) return;
    int b = batch[n];
    int prev = (n == 0) ? -1 : batch[n - 1];
    for (int g = prev + 1; g <= b; g++) gstart[g] = n;
    if (n == NN - 1) {
        for (int g = b + 1; g <= NG; g++) gstart[g] = NN;
    }
}

// ============ LDS helpers (128-row tile, 64 KB) ============
// stage layout: f32x4 slot [row][c4phys], c4phys = c4 ^ (row & 7)
__device__ inline void frag_from_lds(const f32x4* hl, int rl, int kk, int kg,
                                     bf16x8& th, bf16x8& tl) {
    int s = rl & 7;
    int c0 = kk * 8 + kg * 2;
    f32x4 lo = hl[rl * 32 + (c0 ^ s)];
    f32x4 hi = hl[rl * 32 + ((c0 + 1) ^ s)];
    float v[8] = {lo[0], lo[1], lo[2], lo[3], hi[0], hi[1], hi[2], hi[3]};
#pragma unroll
    for (int j = 0; j < 8; j++) {
        short h = bfr(v[j]);
        th[j] = h;
        tl[j] = bfr(v[j] - bf2f(h));
    }
}

// single GEMM (init linear): C = A@W + bias; 128 rows/block
template <int RELU>
__global__ __launch_bounds__(256) void mm_kernel(const float* __restrict__ A,
                                                 float* __restrict__ C,
                                                 const bf16x8* __restrict__ Wph,
                                                 const bf16x8* __restrict__ Wpl,
                                                 const float* __restrict__ sc,
                                                 const float* __restrict__ bb) {
    __shared__ f32x4 hl[128 * 32];  // 64 KB
    float* hf = (float*)hl;
    int t = threadIdx.x;
    int lane = t & 63, wid = t >> 6;
    int row0 = blockIdx.x * 128;
    int r16 = lane & 15, kg = lane >> 4;
    int sc4 = t & 31, srb = t >> 5;

#pragma unroll
    for (int it = 0; it < 16; it++) {
        int r = it * 8 + srb;
        hl[r * 32 + (sc4 ^ (r & 7))] = *(const f32x4*)&A[(size_t)(row0 + r) * DD + sc4 * 4];
    }
    __syncthreads();

    f32x4 acc[2][8];
#pragma unroll
    for (int m = 0; m < 2; m++)
#pragma unroll
        for (int c = 0; c < 8; c++) acc[m][c] = (f32x4){0.f, 0.f, 0.f, 0.f};
#pragma unroll
    for (int kk = 0; kk < 4; kk++) {
        bf16x8 ah[2], al[2];
#pragma unroll
        for (int m = 0; m < 2; m++)
            frag_from_lds(hl, wid * 32 + m * 16 + r16, kk, kg, ah[m], al[m]);
#pragma unroll
        for (int c = 0; c < 8; c++) {
            bf16x8 wh = Wph[kk * 512 + c * 64 + lane];
            bf16x8 wl = Wpl[kk * 512 + c * 64 + lane];
#pragma unroll
            for (int m = 0; m < 2; m++) {
                acc[m][c] = __builtin_amdgcn_mfma_f32_16x16x32_bf16(ah[m], wh, acc[m][c], 0, 0, 0);
                acc[m][c] = __builtin_amdgcn_mfma_f32_16x16x32_bf16(al[m], wh, acc[m][c], 0, 0, 0);
                acc[m][c] = __builtin_amdgcn_mfma_f32_16x16x32_bf16(ah[m], wl, acc[m][c], 0, 0, 0);
            }
        }
    }
    __syncthreads();
#pragma unroll
    for (int c = 0; c < 8; c++) {
        int col = c * 16 + r16;
        float s = sc[col], o = bb[col];
#pragma unroll
        for (int m = 0; m < 2; m++) {
#pragma unroll
            for (int j = 0; j < 4; j++) {
                int rl = wid * 32 + m * 16 + kg * 4 + j;
                float v = acc[m][c][j] * s + o;
                if (RELU) v = fmaxf(v, 0.f);
                hf[rl * 128 + (col ^ ((rl & 7) << 2))] = v;
            }
        }
    }
    __syncthreads();
#pragma unroll
    for (int it = 0; it < 16; it++) {
        int r = it * 8 + srb;
        int row = row0 + r;
        if (row < NN)
            *(f32x4*)&C[(size_t)row * DD + sc4 * 4] = hl[r * 32 + (sc4 ^ (r & 7))];
    }
}

// ============ fused GIN layer ============
// Aout = relu(bn2( relu(bn1( ((1+eps)Ain + gather-sum) @W1 )) @W2 ))
// also: P[g][d] = max over layer-output rows (atomicMax on int bits, values >= 0)
__global__ __launch_bounds__(256) void layer_kernel(
    const float* __restrict__ Ain, float* __restrict__ Aout,
    const int* __restrict__ rowptr, const int* __restrict__ csr_src,
    const int* __restrict__ batchArr, const float* __restrict__ gin_eps, int li,
    const bf16x8* __restrict__ Wph1, const bf16x8* __restrict__ Wpl1,
    const bf16x8* __restrict__ Wph2, const bf16x8* __restrict__ Wpl2,
    const float* __restrict__ sc1, const float* __restrict__ bb1,
    const float* __restrict__ sc2, const float* __restrict__ bb2,
    float* __restrict__ P) {
    __shared__ f32x4 hl[128 * 32];  // 64 KB, reused across phases
    float* hf = (float*)hl;
    int t = threadIdx.x;
    int lane = t & 63, wid = t >> 6;
    int row0 = blockIdx.x * 128;
    int r16 = lane & 15, kg = lane >> 4;
    int sc4 = t & 31, srb = t >> 5;
    const f32x4* A4 = (const f32x4*)Ain;
    float e1 = 1.f + gin_eps[li];

    // ---- phase 1: aggregation -> LDS (swizzled) ----
#pragma unroll
    for (int it = 0; it < 16; it++) {
        int r = it * 8 + srb;
        int n = row0 + r;
        f32x4 acc = (f32x4){0.f, 0.f, 0.f, 0.f};
        if (n < NN) {
            acc = A4[((size_t)n << 5) + sc4] * e1;
            int s = rowptr[n], e = rowptr[n + 1];
            int i = s;
            for (; i + 4 <= e; i += 4) {
                int j0 = csr_src[i];
                int j1 = csr_src[i + 1];
                int j2 = csr_src[i + 2];
                int j3 = csr_src[i + 3];
                f32x4 v0 = A4[((size_t)j0 << 5) + sc4];
                f32x4 v1 = A4[((size_t)j1 << 5) + sc4];
                f32x4 v2 = A4[((size_t)j2 << 5) + sc4];
                f32x4 v3 = A4[((size_t)j3 << 5) + sc4];
                acc += (v0 + v1) + (v2 + v3);
            }
            for (; i < e; i++) acc += A4[((size_t)csr_src[i] << 5) + sc4];
        }
        hl[r * 32 + (sc4 ^ (r & 7))] = acc;
    }
    __syncthreads();

    f32x4 acc[2][8];
#pragma unroll
    for (int m = 0; m < 2; m++)
#pragma unroll
        for (int c = 0; c < 8; c++) acc[m][c] = (f32x4){0.f, 0.f, 0.f, 0.f};

    // ---- GEMM1 ----
#pragma unroll
    for (int kk = 0; kk < 4; kk++) {
        bf16x8 ah[2], al[2];
#pragma unroll
        for (int m = 0; m < 2; m++)
            frag_from_lds(hl, wid * 32 + m * 16 + r16, kk, kg, ah[m], al[m]);
#pragma unroll
        for (int c = 0; c < 8; c++) {
            bf16x8 wh = Wph1[kk * 512 + c * 64 + lane];
            bf16x8 wl = Wpl1[kk * 512 + c * 64 + lane];
#pragma unroll
            for (int m = 0; m < 2; m++) {
                acc[m][c] = __builtin_amdgcn_mfma_f32_16x16x32_bf16(ah[m], wh, acc[m][c], 0, 0, 0);
                acc[m][c] = __builtin_amdgcn_mfma_f32_16x16x32_bf16(al[m], wh, acc[m][c], 0, 0, 0);
                acc[m][c] = __builtin_amdgcn_mfma_f32_16x16x32_bf16(ah[m], wl, acc[m][c], 0, 0, 0);
            }
        }
    }
    __syncthreads();
    // epilogue1: relu(bn1) -> LDS
#pragma unroll
    for (int c = 0; c < 8; c++) {
        int col = c * 16 + r16;
        float s = sc1[col], o = bb1[col];
#pragma unroll
        for (int m = 0; m < 2; m++) {
#pragma unroll
            for (int j = 0; j < 4; j++) {
                int rl = wid * 32 + m * 16 + kg * 4 + j;
                hf[rl * 128 + (col ^ ((rl & 7) << 2))] = fmaxf(acc[m][c][j] * s + o, 0.f);
            }
        }
    }
    __syncthreads();

    // ---- GEMM2 ----
#pragma unroll
    for (int m = 0; m < 2; m++)
#pragma unroll
        for (int c = 0; c < 8; c++) acc[m][c] = (f32x4){0.f, 0.f, 0.f, 0.f};
#pragma unroll
    for (int kk = 0; kk < 4; kk++) {
        bf16x8 ah[2], al[2];
#pragma unroll
        for (int m = 0; m < 2; m++)
            frag_from_lds(hl, wid * 32 + m * 16 + r16, kk, kg, ah[m], al[m]);
#pragma unroll
        for (int c = 0; c < 8; c++) {
            bf16x8 wh = Wph2[kk * 512 + c * 64 + lane];
            bf16x8 wl = Wpl2[kk * 512 + c * 64 + lane];
#pragma unroll
            for (int m = 0; m < 2; m++) {
                acc[m][c] = __builtin_amdgcn_mfma_f32_16x16x32_bf16(ah[m], wh, acc[m][c], 0, 0, 0);
                acc[m][c] = __builtin_amdgcn_mfma_f32_16x16x32_bf16(al[m], wh, acc[m][c], 0, 0, 0);
                acc[m][c] = __builtin_amdgcn_mfma_f32_16x16x32_bf16(ah[m], wl, acc[m][c], 0, 0, 0);
            }
        }
    }
    __syncthreads();
    // epilogue2: relu(bn2) -> LDS
#pragma unroll
    for (int c = 0; c < 8; c++) {
        int col = c * 16 + r16;
        float s = sc2[col], o = bb2[col];
#pragma unroll
        for (int m = 0; m < 2; m++) {
#pragma unroll
            for (int j = 0; j < 4; j++) {
                int rl = wid * 32 + m * 16 + kg * 4 + j;
                hf[rl * 128 + (col ^ ((rl & 7) << 2))] = fmaxf(acc[m][c][j] * s + o, 0.f);
            }
        }
    }
    __syncthreads();

    // ---- store Aout (coalesced) ----
#pragma unroll
    for (int it = 0; it < 16; it++) {
        int r = it * 8 + srb;
        int row = row0 + r;
        if (row < NN)
            *(f32x4*)&Aout[(size_t)row * DD + sc4 * 4] = hl[r * 32 + (sc4 ^ (r & 7))];
    }

    // ---- pooled max into P (values >= 0 -> int atomicMax valid) ----
    {
        int d = t & 127;
        int half = t >> 7;  // rows [half*64, half*64+64)
        int curg = -1;
        float m = 0.f;
        for (int r = half * 64; r < half * 64 + 64; r++) {
            int row = row0 + r;
            if (row >= NN) break;
            int g = batchArr[row];
            if (g != curg) {
                if (curg >= 0)
                    atomicMax((int*)&P[(size_t)curg * DD + d], __float_as_int(m));
                curg = g;
                m = 0.f;
            }
            float v = hf[r * 128 + (d ^ ((r & 7) << 2))];
            m = fmaxf(m, v);
        }
        if (curg >= 0) atomicMax((int*)&P[(size_t)curg * DD + d], __float_as_int(m));
    }
}

// ---------------- pool (range-based) -> OUT[g][d] = max ----------------
__global__ void pool0_kernel(const float* __restrict__ X, const int* __restrict__ gstart,
                             float* __restrict__ OUT) {
    int gph = blockIdx.x;
    int d = threadIdx.x;  // 128
    int start = gstart[gph], end = gstart[gph + 1];
    float m;
    if (start >= end) {
        m = 0.f;
    } else {
        m = -INFINITY;
        for (int n = start; n < end; n++) m = fmaxf(m, X[(size_t)n * DD + d]);
    }
    OUT[(size_t)gph * DD + d] = m;
}

// ------- linear-accumulate: OUT[g] += P[g] @ W + b  (4 graphs/block) -------
__global__ __launch_bounds__(128) void linacc_kernel(const float* __restrict__ P,
                                                     const float* __restrict__ W,
                                                     const float* __restrict__ b,
                                                     float* __restrict__ OUT) {
    __shared__ float p[4][DD];
    int g0 = blockIdx.x * 4;
    int d = threadIdx.x;
#pragma unroll
    for (int gg = 0; gg < 4; gg++) p[gg][d] = P[(size_t)(g0 + gg) * DD + d];
    __syncthreads();
    float acc0 = b[d], acc1 = b[d], acc2 = b[d], acc3 = b[d];
#pragma unroll 8
    for (int k = 0; k < DD; k++) {
        float w = W[k * DD + d];
        acc0 += p[0][k] * w;
        acc1 += p[1][k] * w;
        acc2 += p[2][k] * w;
        acc3 += p[3][k] * w;
    }
    OUT[(size_t)(g0 + 0) * DD + d] += acc0;
    OUT[(size_t)(g0 + 1) * DD + d] += acc1;
    OUT[(size_t)(g0 + 2) * DD + d] += acc2;
    OUT[(size_t)(g0 + 3) * DD + d] += acc3;
}

// ---------------- post MLP -> scalar per graph ----------------
__global__ void post_kernel(const float* __restrict__ OUT, const float* __restrict__ W1,
                            const float* __restrict__ b1, const float* __restrict__ W2,
                            const float* __restrict__ b2, float* __restrict__ S) {
    __shared__ float o[DD];
    __shared__ float red[2];
    int gph = blockIdx.x, d = threadIdx.x;
    o[d] = fmaxf(OUT[(size_t)gph * DD + d], 0.f);
    __syncthreads();
    float acc = b1[d];
#pragma unroll 8
    for (int k = 0; k < DD; k++) acc += o[k] * W1[k * DD + d];
    acc = fmaxf(acc, 0.f);
    float v = acc * W2[d];
#pragma unroll
    for (int off = 32; off > 0; off >>= 1) v += __shfl_down(v, off);
    if ((d & 63) == 0) red[d >> 6] = v;
    __syncthreads();
    if (d == 0) S[gph] = red[0] + red[1] + b2[0];
}

// ---------------- decode ----------------
__global__ void pred_kernel(const int* __restrict__ eil, const int* __restrict__ el,
                            const float* __restrict__ S, float* __restrict__ out) {
    int i = blockIdx.x * blockDim.x + threadIdx.x;
    if (i >= NEL) return;
    int a = eil[i], b = eil[NEL + i];
    out[i] = S[a] * S[b];
    out[NEL + i] = (float)el[i];
}

extern "C" void kernel_launch(void* const* d_in, const int* in_sizes, int n_in,
                              void* d_out, int out_size, void* d_ws, size_t ws_size,
                              hipStream_t stream) {
    const float* x = (const float*)d_in[0];
    const int* edge_index = (const int*)d_in[1];
    const int* batch = (const int*)d_in[2];
    const int* eil = (const int*)d_in[3];
    const int* el = (const int*)d_in[4];
    const float* encW = (const float*)d_in[5];
    const float* encb = (const float*)d_in[6];
    const float* initW = (const float*)d_in[7];
    const float* initb = (const float*)d_in[8];
    const float* gin_eps = (const float*)d_in[9];
    const float* W1 = (const float*)d_in[10];
    const float* b1 = (const float*)d_in[11];
    const float* g1 = (const float*)d_in[12];
    const float* be1 = (const float*)d_in[13];
    const float* rm1 = (const float*)d_in[14];
    const float* rv1 = (const float*)d_in[15];
    const float* W2 = (const float*)d_in[16];
    const float* b2 = (const float*)d_in[17];
    const float* g2 = (const float*)d_in[18];
    const float* be2 = (const float*)d_in[19];
    const float* rm2 = (const float*)d_in[20];
    const float* rv2 = (const float*)d_in[21];
    const float* linW = (const float*)d_in[22];
    const float* linb = (const float*)d_in[23];
    const float* postW1 = (const float*)d_in[24];
    const float* postb1 = (const float*)d_in[25];
    const float* postW2 = (const float*)d_in[26];
    const float* postb2 = (const float*)d_in[27];

    const int* srcArr = edge_index;
    const int* dstArr = edge_index + NE;

    // workspace carve (256B aligned)
    char* w = (char*)d_ws;
    auto carve = [&](size_t bytes) -> char* {
        char* p = w;
        w += (bytes + 255) & ~(size_t)255;
        return p;
    };
    float* A = (float*)carve((size_t)NP * DD * 4);
    float* B = (float*)carve((size_t)NP * DD * 4);
    float* OUTb = (float*)carve((size_t)NG * DD * 4);
    float* P = (float*)carve((size_t)NG * DD * 4);
    float* S = (float*)carve((size_t)NG * 4);
    int* deg = (int*)carve((size_t)NN * 4);
    int* rowptr = (int*)carve((size_t)(NN + 1) * 4);
    int* cursor = (int*)carve((size_t)NN * 4);
    int* csr_src = (int*)carve((size_t)NE * 4);
    int* bsum = (int*)carve((size_t)NB_SCAN * 4);
    int* boff = (int*)carve((size_t)NB_SCAN * 4);
    int* gstart = (int*)carve((size_t)(NG + 1) * 4);
    bf16x8* Wph = (bf16x8*)carve((size_t)9 * 2048 * 16);
    bf16x8* Wpl = (bf16x8*)carve((size_t)9 * 2048 * 16);
    float* scv = (float*)carve((size_t)9 * DD * 4);
    float* bbv = (float*)carve((size_t)9 * DD * 4);

    float* out = (float*)d_out;
    const int tileBlk = NP / 128;  // 1172

    // ---- prep (weights pack + BN fold) ----
    prep_w_kernel<<<72, 256, 0, stream>>>(initW, W1, W2, Wph, Wpl);
    prep_scb_kernel<<<5, 256, 0, stream>>>(initb, b1, g1, be1, rm1, rv1,
                                           b2, g2, be2, rm2, rv2, scv, bbv);

    // ---- CSR build (once, reused across 4 layers) ----
    zero_int_kernel<<<586, 256, 0, stream>>>(deg, NN);
    hist_kernel<<<2344, 256, 0, stream>>>(dstArr, deg);
    scan_reduce_kernel<<<NB_SCAN, 256, 0, stream>>>(deg, bsum);
    scan_mid_kernel<<<1, 256, 0, stream>>>(bsum, boff, rowptr + NN);
    scan_final_kernel<<<NB_SCAN, 256, 0, stream>>>(deg, boff, rowptr);
    copy_int_kernel<<<586, 256, 0, stream>>>(rowptr, cursor, NN);
    fill_kernel<<<2344, 256, 0, stream>>>(srcArr, dstArr, cursor, csr_src);
    gstart_kernel<<<586, 256, 0, stream>>>(batch, gstart);

    // ---- encoder -> A ----
    enc_kernel<<<tileBlk, 256, 0, stream>>>(x, encW, encb, A);
    // B = A @ initW + initb   (mat 0, no relu)
    mm_kernel<0><<<tileBlk, 256, 0, stream>>>(A, B, Wph, Wpl, scv, bbv);
    // OUT = pool(B)
    pool0_kernel<<<NG, DD, 0, stream>>>(B, gstart, OUTb);

    float* pin = A;
    float* pout = B;
    for (int i = 0; i < NL; i++) {
        zero_f4_kernel<<<(NG * DD / 4) / 256, 256, 0, stream>>>((float4*)P, NG * DD / 4);
        layer_kernel<<<tileBlk, 256, 0, stream>>>(
            pin, pout, rowptr, csr_src, batch, gin_eps, i,
            Wph + (size_t)(1 + i) * 2048, Wpl + (size_t)(1 + i) * 2048,
            Wph + (size_t)(5 + i) * 2048, Wpl + (size_t)(5 + i) * 2048,
            scv + (1 + i) * DD, bbv + (1 + i) * DD,
            scv + (5 + i) * DD, bbv + (5 + i) * DD, P);
        linacc_kernel<<<NG / 4, DD, 0, stream>>>(P, linW + (size_t)i * DD * DD,
                                                 linb + i * DD, OUTb);
        float* tmp = pin; pin = pout; pout = tmp;
    }

    post_kernel<<<NG, DD, 0, stream>>>(OUTb, postW1, postb1, postW2, postb2, S);
    pred_kernel<<<(NEL + 255) / 256, 256, 0, stream>>>(eil, el, S, out);
}

// Round 9
// 1285.316 us; speedup vs baseline: 1.2577x; 1.2577x over previous
//
#include <hip/hip_runtime.h>

#define NN 150000
#define NP 150016   // NN padded to multiple of 128
#define NE 600000
#define NG 8192
#define DD 128
#define FINN 16
#define NL 4
#define NEL 500000
#define BN_EPS 1e-5f
#define NB_SCAN 147  // ceil(NN/1024)
#define ENC_NEG_INF 0x007FFFFFu  // fenc(-inf)

typedef __attribute__((ext_vector_type(8))) short bf16x8;
typedef __attribute__((ext_vector_type(4))) float f32x4;

__device__ inline short bfr(float x) {
    unsigned u = __builtin_bit_cast(unsigned, x);
    unsigned r = u + 0x7fffu + ((u >> 16) & 1u);
    return (short)(r >> 16);
}
__device__ inline float bf2f(short h) {
    return __builtin_bit_cast(float, ((unsigned)(unsigned short)h) << 16);
}
// monotone float<->uint encode for atomicMax over signed floats
__device__ inline unsigned fenc(float f) {
    unsigned b = __float_as_uint(f);
    return (b & 0x80000000u) ? ~b : (b | 0x80000000u);
}
__device__ inline float fdec(unsigned k) {
    unsigned b = (k & 0x80000000u) ? (k ^ 0x80000000u) : ~k;
    return __uint_as_float(b);
}

// ------- pack 9 weight matrices into MFMA B-fragment layout, hi+lo split -------
__global__ void prep_w_kernel(const float* __restrict__ initW, const float* __restrict__ W1,
                              const float* __restrict__ W2, bf16x8* __restrict__ Wph,
                              bf16x8* __restrict__ Wpl) {
    int tid = blockIdx.x * 256 + threadIdx.x;  // 9*2048 = 18432
    if (tid >= 9 * 2048) return;
    int mat = tid >> 11;
    int rem = tid & 2047;
    int kk = rem >> 9;
    int c = (rem >> 6) & 7;
    int lane = rem & 63;
    const float* Wm;
    if (mat == 0) Wm = initW;
    else if (mat <= 4) Wm = W1 + (size_t)(mat - 1) * DD * DD;
    else Wm = W2 + (size_t)(mat - 5) * DD * DD;
    int col = c * 16 + (lane & 15);
    int kbase = kk * 32 + (lane >> 4) * 8;
    bf16x8 oh, ol;
#pragma unroll
    for (int j = 0; j < 8; j++) {
        float v = Wm[(size_t)(kbase + j) * DD + col];
        short h = bfr(v);
        oh[j] = h;
        ol[j] = bfr(v - bf2f(h));
    }
    Wph[tid] = oh;
    Wpl[tid] = ol;
}

// ---------------- fold BN into per-column scale/bias ----------------
__global__ void prep_scb_kernel(const float* __restrict__ initb,
                                const float* __restrict__ b1, const float* __restrict__ g1,
                                const float* __restrict__ be1, const float* __restrict__ rm1,
                                const float* __restrict__ rv1,
                                const float* __restrict__ b2, const float* __restrict__ g2,
                                const float* __restrict__ be2, const float* __restrict__ rm2,
                                const float* __restrict__ rv2,
                                float* __restrict__ sc, float* __restrict__ bb) {
    int tid = blockIdx.x * 256 + threadIdx.x;  // 9*128
    if (tid >= 9 * DD) return;
    int mat = tid >> 7, d = tid & 127;
    float s, o;
    if (mat == 0) {
        s = 1.f;
        o = initb[d];
    } else {
        const float *b_, *g_, *be_, *rm_, *rv_;
        int i;
        if (mat <= 4) { i = mat - 1; b_ = b1; g_ = g1; be_ = be1; rm_ = rm1; rv_ = rv1; }
        else          { i = mat - 5; b_ = b2; g_ = g2; be_ = be2; rm_ = rm2; rv_ = rv2; }
        float t = g_[i * DD + d] * rsqrtf(rv_[i * DD + d] + BN_EPS);
        s = t;
        o = (b_[i * DD + d] - rm_[i * DD + d]) * t + be_[i * DD + d];
    }
    sc[tid] = s;
    bb[tid] = o;
}

// ---------------- utility fills ----------------
__global__ void fillpat_kernel(unsigned* __restrict__ p, unsigned v, int n) {
    int i = blockIdx.x * 256 + threadIdx.x;
    if (i < n) p[i] = v;
}

// ---------------- CSR build ----------------
__global__ void zero_int_kernel(int* __restrict__ p, int n) {
    int i = blockIdx.x * 256 + threadIdx.x;
    if (i < n) p[i] = 0;
}

__global__ void hist_kernel(const int* __restrict__ dst, int* __restrict__ deg) {
    int e = blockIdx.x * 256 + threadIdx.x;
    if (e < NE) atomicAdd(&deg[dst[e]], 1);
}

__global__ void scan_reduce_kernel(const int* __restrict__ deg, int* __restrict__ bsum) {
    __shared__ int s[256];
    int b = blockIdx.x, t = threadIdx.x;
    int base = b * 1024 + t * 4;
    int v = 0;
#pragma unroll
    for (int i = 0; i < 4; i++) {
        int idx = base + i;
        if (idx < NN) v += deg[idx];
    }
    s[t] = v;
    __syncthreads();
    for (int off = 128; off > 0; off >>= 1) {
        if (t < off) s[t] += s[t + off];
        __syncthreads();
    }
    if (t == 0) bsum[b] = s[0];
}

__global__ void scan_mid_kernel(const int* __restrict__ bsum, int* __restrict__ boff,
                                int* __restrict__ rowptrN) {
    __shared__ int s[256];
    int t = threadIdx.x;
    int v = (t < NB_SCAN) ? bsum[t] : 0;
    s[t] = v;
    __syncthreads();
    for (int off = 1; off < 256; off <<= 1) {
        int u = (t >= off) ? s[t - off] : 0;
        __syncthreads();
        s[t] += u;
        __syncthreads();
    }
    if (t < NB_SCAN) boff[t] = s[t] - v;
    if (t == 255) *rowptrN = s[255];
}

__global__ void scan_final_kernel(const int* __restrict__ deg, const int* __restrict__ boff,
                                  int* __restrict__ rowptr) {
    __shared__ int s[256];
    int b = blockIdx.x, t = threadIdx.x;
    int base = b * 1024 + t * 4;
    int v[4];
    int sum = 0;
#pragma unroll
    for (int i = 0; i < 4; i++) {
        int idx = base + i;
        v[i] = (idx < NN) ? deg[idx] : 0;
        sum += v[i];
    }
    s[t] = sum;
    __syncthreads();
    int my = sum;
    for (int off = 1; off < 256; off <<= 1) {
        int u = (t >= off) ? s[t - off] : 0;
        __syncthreads();
        s[t] += u;
        __syncthreads();
    }
    int excl = s[t] - my + boff[b];
#pragma unroll
    for (int i = 0; i < 4; i++) {
        int idx = base + i;
        if (idx < NN) rowptr[idx] = excl;
        excl += v[i];
    }
}

__global__ void copy_int_kernel(const int* __restrict__ a, int* __restrict__ b, int n) {
    int i = blockIdx.x * 256 + threadIdx.x;
    if (i < n) b[i] = a[i];
}

__global__ void fill_kernel(const int* __restrict__ src, const int* __restrict__ dst,
                            int* cursor, int* __restrict__ csr_src) {
    int e = blockIdx.x * 256 + threadIdx.x;
    if (e >= NE) return;
    int p = atomicAdd(&cursor[dst[e]], 1);
    csr_src[p] = src[e];
}

// ------- fused GIN aggregation: B[n] = (1+eps)*A[n] + sum_{j in N(n)} A[j] -------
__global__ __launch_bounds__(256) void agg_kernel(const f32x4* __restrict__ A4,
                                                  const int* __restrict__ rowptr,
                                                  const int* __restrict__ csr_src,
                                                  const float* __restrict__ gin_eps,
                                                  int li, f32x4* __restrict__ B4) {
    int n = blockIdx.x * 8 + (threadIdx.x >> 5);  // grid = NN/8 exactly
    int c = threadIdx.x & 31;
    float e1 = 1.f + gin_eps[li];
    int s = rowptr[n], e = rowptr[n + 1];
    int base = n << 5;
    f32x4 acc = A4[base + c] * e1;
    int i = s;
    for (; i + 4 <= e; i += 4) {
        int j0 = csr_src[i];
        int j1 = csr_src[i + 1];
        int j2 = csr_src[i + 2];
        int j3 = csr_src[i + 3];
        f32x4 v0 = A4[(j0 << 5) + c];
        f32x4 v1 = A4[(j1 << 5) + c];
        f32x4 v2 = A4[(j2 << 5) + c];
        f32x4 v3 = A4[(j3 << 5) + c];
        acc += (v0 + v1) + (v2 + v3);
    }
    for (; i < e; i++) acc += A4[(csr_src[i] << 5) + c];
    B4[base + c] = acc;
}

// ============ LDS fragment helper (swizzled f32x4 tile) ============
__device__ inline void frag_from_lds(const f32x4* hl, int rl, int kk, int kg,
                                     bf16x8& th, bf16x8& tl) {
    int s = rl & 7;
    int c0 = kk * 8 + kg * 2;
    f32x4 lo = hl[rl * 32 + (c0 ^ s)];
    f32x4 hi = hl[rl * 32 + ((c0 + 1) ^ s)];
    float v[8] = {lo[0], lo[1], lo[2], lo[3], hi[0], hi[1], hi[2], hi[3]};
#pragma unroll
    for (int j = 0; j < 8; j++) {
        short h = bfr(v[j]);
        th[j] = h;
        tl[j] = bfr(v[j] - bf2f(h));
    }
}

// ============ fused encoder + init GEMM + init pool ============
// A = x@encW+encb (written to global); t = A@initW+initb (LDS only);
// P0enc[g][d] = atomicMax-encoded max over t rows.  B never materialized.
__global__ __launch_bounds__(256) void init_fused_kernel(
    const float* __restrict__ x, const float* __restrict__ encW,
    const float* __restrict__ encb, const int* __restrict__ batchArr,
    const bf16x8* __restrict__ Wph, const bf16x8* __restrict__ Wpl,
    const float* __restrict__ sc, const float* __restrict__ bb,
    float* __restrict__ A, unsigned* __restrict__ P0enc) {
    __shared__ f32x4 hl[128 * 32];  // 64 KB
    float* hf = (float*)hl;
    int t = threadIdx.x;
    int lane = t & 63, wid = t >> 6;
    int row0 = blockIdx.x * 128;
    int r16 = lane & 15, kg = lane >> 4;
    int sc4 = t & 31, srb = t >> 5;

    // ---- phase 1: encoder -> LDS (+ global A) ----
    {
        int c4 = sc4 * 4;
        float4 wreg[16];
#pragma unroll
        for (int k = 0; k < 16; k++) wreg[k] = *(const float4*)&encW[k * DD + c4];
        float4 bias = *(const float4*)&encb[c4];
#pragma unroll
        for (int it = 0; it < 16; it++) {
            int r = it * 8 + srb;
            int row = row0 + r;
            f32x4 accv = (f32x4){0.f, 0.f, 0.f, 0.f};
            if (row < NN) {
                const float4* xr = (const float4*)(x + (size_t)row * FINN);
                float4 x0 = xr[0], x1 = xr[1], x2 = xr[2], x3 = xr[3];
                float xs[16] = {x0.x, x0.y, x0.z, x0.w, x1.x, x1.y, x1.z, x1.w,
                                x2.x, x2.y, x2.z, x2.w, x3.x, x3.y, x3.z, x3.w};
                float4 a = bias;
#pragma unroll
                for (int k = 0; k < 16; k++) {
                    a.x += xs[k] * wreg[k].x;
                    a.y += xs[k] * wreg[k].y;
                    a.z += xs[k] * wreg[k].z;
                    a.w += xs[k] * wreg[k].w;
                }
                accv = (f32x4){a.x, a.y, a.z, a.w};
                *(f32x4*)&A[(size_t)row * DD + c4] = accv;
            }
            hl[r * 32 + (sc4 ^ (r & 7))] = accv;
        }
    }
    __syncthreads();

    // ---- phase 2: GEMM (x_feat @ initW) ----
    f32x4 acc[2][8];
#pragma unroll
    for (int m = 0; m < 2; m++)
#pragma unroll
        for (int c = 0; c < 8; c++) acc[m][c] = (f32x4){0.f, 0.f, 0.f, 0.f};
#pragma unroll
    for (int kk = 0; kk < 4; kk++) {
        bf16x8 ah[2], al[2];
#pragma unroll
        for (int m = 0; m < 2; m++)
            frag_from_lds(hl, wid * 32 + m * 16 + r16, kk, kg, ah[m], al[m]);
#pragma unroll
        for (int c = 0; c < 8; c++) {
            bf16x8 wh = Wph[kk * 512 + c * 64 + lane];
            bf16x8 wl = Wpl[kk * 512 + c * 64 + lane];
#pragma unroll
            for (int m = 0; m < 2; m++) {
                acc[m][c] = __builtin_amdgcn_mfma_f32_16x16x32_bf16(ah[m], wh, acc[m][c], 0, 0, 0);
                acc[m][c] = __builtin_amdgcn_mfma_f32_16x16x32_bf16(al[m], wh, acc[m][c], 0, 0, 0);
                acc[m][c] = __builtin_amdgcn_mfma_f32_16x16x32_bf16(ah[m], wl, acc[m][c], 0, 0, 0);
            }
        }
    }
    __syncthreads();
    // epilogue (bias, no relu) -> LDS
#pragma unroll
    for (int c = 0; c < 8; c++) {
        int col = c * 16 + r16;
        float s = sc[col], o = bb[col];
#pragma unroll
        for (int m = 0; m < 2; m++) {
#pragma unroll
            for (int j = 0; j < 4; j++) {
                int rl = wid * 32 + m * 16 + kg * 4 + j;
                hf[rl * 128 + (col ^ ((rl & 7) << 2))] = acc[m][c][j] * s + o;
            }
        }
    }
    __syncthreads();

    // ---- phase 3: pooled max (encoded atomicMax, values may be negative) ----
    {
        int d = t & 127;
        int half = t >> 7;
        int curg = -1;
        float m = -INFINITY;
        for (int r = half * 64; r < half * 64 + 64; r++) {
            int row = row0 + r;
            if (row >= NN) break;
            int g = batchArr[row];
            if (g != curg) {
                if (curg >= 0)
                    atomicMax(&P0enc[(size_t)curg * DD + d], fenc(m));
                curg = g;
                m = -INFINITY;
            }
            m = fmaxf(m, hf[r * 128 + (d ^ ((r & 7) << 2))]);
        }
        if (curg >= 0) atomicMax(&P0enc[(size_t)curg * DD + d], fenc(m));
    }
}

// ---------------- decode init pool -> OUTb (empty graphs -> 0) ----------------
__global__ void decode_kernel(const unsigned* __restrict__ P0enc, float* __restrict__ OUT) {
    int i = blockIdx.x * 256 + threadIdx.x;
    if (i >= NG * DD) return;
    unsigned k = P0enc[i];
    float f = fdec(k);
    OUT[i] = (k == ENC_NEG_INF) ? 0.f : f;
}

// ============ fused double GEMM + layer pool ============
// Aout = relu(bn2( relu(bn1(Ain@W1)) @ W2 ));  P[g][d] = max (int atomicMax, >=0)
__global__ __launch_bounds__(256) void mm2xp_kernel(
    const float* __restrict__ Ain, float* __restrict__ Aout,
    const int* __restrict__ batchArr,
    const bf16x8* __restrict__ Wph1, const bf16x8* __restrict__ Wpl1,
    const bf16x8* __restrict__ Wph2, const bf16x8* __restrict__ Wpl2,
    const float* __restrict__ sc1, const float* __restrict__ bb1,
    const float* __restrict__ sc2, const float* __restrict__ bb2,
    float* __restrict__ P) {
    __shared__ f32x4 hl[128 * 32];  // 64 KB
    float* hf = (float*)hl;
    int t = threadIdx.x;
    int lane = t & 63, wid = t >> 6;
    int row0 = blockIdx.x * 128;
    int r16 = lane & 15, kg = lane >> 4;
    int sc4 = t & 31, srb = t >> 5;

    // stage Ain -> LDS
#pragma unroll
    for (int it = 0; it < 16; it++) {
        int r = it * 8 + srb;
        hl[r * 32 + (sc4 ^ (r & 7))] = *(const f32x4*)&Ain[(size_t)(row0 + r) * DD + sc4 * 4];
    }
    __syncthreads();

    f32x4 acc[2][8];
#pragma unroll
    for (int m = 0; m < 2; m++)
#pragma unroll
        for (int c = 0; c < 8; c++) acc[m][c] = (f32x4){0.f, 0.f, 0.f, 0.f};

    // ---- GEMM1 ----
#pragma unroll
    for (int kk = 0; kk < 4; kk++) {
        bf16x8 ah[2], al[2];
#pragma unroll
        for (int m = 0; m < 2; m++)
            frag_from_lds(hl, wid * 32 + m * 16 + r16, kk, kg, ah[m], al[m]);
#pragma unroll
        for (int c = 0; c < 8; c++) {
            bf16x8 wh = Wph1[kk * 512 + c * 64 + lane];
            bf16x8 wl = Wpl1[kk * 512 + c * 64 + lane];
#pragma unroll
            for (int m = 0; m < 2; m++) {
                acc[m][c] = __builtin_amdgcn_mfma_f32_16x16x32_bf16(ah[m], wh, acc[m][c], 0, 0, 0);
                acc[m][c] = __builtin_amdgcn_mfma_f32_16x16x32_bf16(al[m], wh, acc[m][c], 0, 0, 0);
                acc[m][c] = __builtin_amdgcn_mfma_f32_16x16x32_bf16(ah[m], wl, acc[m][c], 0, 0, 0);
            }
        }
    }
    __syncthreads();
    // epilogue1: relu(bn1) -> LDS
#pragma unroll
    for (int c = 0; c < 8; c++) {
        int col = c * 16 + r16;
        float s = sc1[col], o = bb1[col];
#pragma unroll
        for (int m = 0; m < 2; m++) {
#pragma unroll
            for (int j = 0; j < 4; j++) {
                int rl = wid * 32 + m * 16 + kg * 4 + j;
                hf[rl * 128 + (col ^ ((rl & 7) << 2))] = fmaxf(acc[m][c][j] * s + o, 0.f);
            }
        }
    }
    __syncthreads();

    // ---- GEMM2 ----
#pragma unroll
    for (int m = 0; m < 2; m++)
#pragma unroll
        for (int c = 0; c < 8; c++) acc[m][c] = (f32x4){0.f, 0.f, 0.f, 0.f};
#pragma unroll
    for (int kk = 0; kk < 4; kk++) {
        bf16x8 ah[2], al[2];
#pragma unroll
        for (int m = 0; m < 2; m++)
            frag_from_lds(hl, wid * 32 + m * 16 + r16, kk, kg, ah[m], al[m]);
#pragma unroll
        for (int c = 0; c < 8; c++) {
            bf16x8 wh = Wph2[kk * 512 + c * 64 + lane];
            bf16x8 wl = Wpl2[kk * 512 + c * 64 + lane];
#pragma unroll
            for (int m = 0; m < 2; m++) {
                acc[m][c] = __builtin_amdgcn_mfma_f32_16x16x32_bf16(ah[m], wh, acc[m][c], 0, 0, 0);
                acc[m][c] = __builtin_amdgcn_mfma_f32_16x16x32_bf16(al[m], wh, acc[m][c], 0, 0, 0);
                acc[m][c] = __builtin_amdgcn_mfma_f32_16x16x32_bf16(ah[m], wl, acc[m][c], 0, 0, 0);
            }
        }
    }
    __syncthreads();
    // epilogue2: relu(bn2) -> LDS
#pragma unroll
    for (int c = 0; c < 8; c++) {
        int col = c * 16 + r16;
        float s = sc2[col], o = bb2[col];
#pragma unroll
        for (int m = 0; m < 2; m++) {
#pragma unroll
            for (int j = 0; j < 4; j++) {
                int rl = wid * 32 + m * 16 + kg * 4 + j;
                hf[rl * 128 + (col ^ ((rl & 7) << 2))] = fmaxf(acc[m][c][j] * s + o, 0.f);
            }
        }
    }
    __syncthreads();
    // coalesced Aout store
#pragma unroll
    for (int it = 0; it < 16; it++) {
        int r = it * 8 + srb;
        int row = row0 + r;
        if (row < NN)
            *(f32x4*)&Aout[(size_t)row * DD + sc4 * 4] = hl[r * 32 + (sc4 ^ (r & 7))];
    }

    // pooled max into P (post-relu values >= 0 -> int atomicMax valid)
    {
        int d = t & 127;
        int half = t >> 7;
        int curg = -1;
        float m = 0.f;
        for (int r = half * 64; r < half * 64 + 64; r++) {
            int row = row0 + r;
            if (row >= NN) break;
            int g = batchArr[row];
            if (g != curg) {
                if (curg >= 0)
                    atomicMax((int*)&P[(size_t)curg * DD + d], __float_as_int(m));
                curg = g;
                m = 0.f;
            }
            m = fmaxf(m, hf[r * 128 + (d ^ ((r & 7) << 2))]);
        }
        if (curg >= 0) atomicMax((int*)&P[(size_t)curg * DD + d], __float_as_int(m));
    }
}

// ------- linear-accumulate: OUT[g] += P[g] @ W + b  (4 graphs/block) -------
__global__ __launch_bounds__(128) void linacc_kernel(const float* __restrict__ P,
                                                     const float* __restrict__ W,
                                                     const float* __restrict__ b,
                                                     float* __restrict__ OUT) {
    __shared__ float p[4][DD];
    int g0 = blockIdx.x * 4;
    int d = threadIdx.x;
#pragma unroll
    for (int gg = 0; gg < 4; gg++) p[gg][d] = P[(size_t)(g0 + gg) * DD + d];
    __syncthreads();
    float acc0 = b[d], acc1 = b[d], acc2 = b[d], acc3 = b[d];
#pragma unroll 8
    for (int k = 0; k < DD; k++) {
        float w = W[k * DD + d];
        acc0 += p[0][k] * w;
        acc1 += p[1][k] * w;
        acc2 += p[2][k] * w;
        acc3 += p[3][k] * w;
    }
    OUT[(size_t)(g0 + 0) * DD + d] += acc0;
    OUT[(size_t)(g0 + 1) * DD + d] += acc1;
    OUT[(size_t)(g0 + 2) * DD + d] += acc2;
    OUT[(size_t)(g0 + 3) * DD + d] += acc3;
}

// ---------------- post MLP -> scalar per graph ----------------
__global__ void post_kernel(const float* __restrict__ OUT, const float* __restrict__ W1,
                            const float* __restrict__ b1, const float* __restrict__ W2,
                            const float* __restrict__ b2, float* __restrict__ S) {
    __shared__ float o[DD];
    __shared__ float red[2];
    int gph = blockIdx.x, d = threadIdx.x;
    o[d] = fmaxf(OUT[(size_t)gph * DD + d], 0.f);
    __syncthreads();
    float acc = b1[d];
#pragma unroll 8
    for (int k = 0; k < DD; k++) acc += o[k] * W1[k * DD + d];
    acc = fmaxf(acc, 0.f);
    float v = acc * W2[d];
#pragma unroll
    for (int off = 32; off > 0; off >>= 1) v += __shfl_down(v, off);
    if ((d & 63) == 0) red[d >> 6] = v;
    __syncthreads();
    if (d == 0) S[gph] = red[0] + red[1] + b2[0];
}

// ---------------- decode edge predictions ----------------
__global__ void pred_kernel(const int* __restrict__ eil, const int* __restrict__ el,
                            const float* __restrict__ S, float* __restrict__ out) {
    int i = blockIdx.x * blockDim.x + threadIdx.x;
    if (i >= NEL) return;
    int a = eil[i], b = eil[NEL + i];
    out[i] = S[a] * S[b];
    out[NEL + i] = (float)el[i];
}

extern "C" void kernel_launch(void* const* d_in, const int* in_sizes, int n_in,
                              void* d_out, int out_size, void* d_ws, size_t ws_size,
                              hipStream_t stream) {
    const float* x = (const float*)d_in[0];
    const int* edge_index = (const int*)d_in[1];
    const int* batch = (const int*)d_in[2];
    const int* eil = (const int*)d_in[3];
    const int* el = (const int*)d_in[4];
    const float* encW = (const float*)d_in[5];
    const float* encb = (const float*)d_in[6];
    const float* initW = (const float*)d_in[7];
    const float* initb = (const float*)d_in[8];
    const float* gin_eps = (const float*)d_in[9];
    const float* W1 = (const float*)d_in[10];
    const float* b1 = (const float*)d_in[11];
    const float* g1 = (const float*)d_in[12];
    const float* be1 = (const float*)d_in[13];
    const float* rm1 = (const float*)d_in[14];
    const float* rv1 = (const float*)d_in[15];
    const float* W2 = (const float*)d_in[16];
    const float* b2 = (const float*)d_in[17];
    const float* g2 = (const float*)d_in[18];
    const float* be2 = (const float*)d_in[19];
    const float* rm2 = (const float*)d_in[20];
    const float* rv2 = (const float*)d_in[21];
    const float* linW = (const float*)d_in[22];
    const float* linb = (const float*)d_in[23];
    const float* postW1 = (const float*)d_in[24];
    const float* postb1 = (const float*)d_in[25];
    const float* postW2 = (const float*)d_in[26];
    const float* postb2 = (const float*)d_in[27];

    const int* srcArr = edge_index;
    const int* dstArr = edge_index + NE;

    // workspace carve (256B aligned)
    char* w = (char*)d_ws;
    auto carve = [&](size_t bytes) -> char* {
        char* p = w;
        w += (bytes + 255) & ~(size_t)255;
        return p;
    };
    float* A = (float*)carve((size_t)NP * DD * 4);
    float* B = (float*)carve((size_t)NP * DD * 4);
    float* OUTb = (float*)carve((size_t)NG * DD * 4);
    float* P = (float*)carve((size_t)NG * DD * 4);  // also P0enc (unsigned)
    float* S = (float*)carve((size_t)NG * 4);
    int* deg = (int*)carve((size_t)NN * 4);
    int* rowptr = (int*)carve((size_t)(NN + 1) * 4);
    int* cursor = (int*)carve((size_t)NN * 4);
    int* csr_src = (int*)carve((size_t)NE * 4);
    int* bsum = (int*)carve((size_t)NB_SCAN * 4);
    int* boff = (int*)carve((size_t)NB_SCAN * 4);
    bf16x8* Wph = (bf16x8*)carve((size_t)9 * 2048 * 16);
    bf16x8* Wpl = (bf16x8*)carve((size_t)9 * 2048 * 16);
    float* scv = (float*)carve((size_t)9 * DD * 4);
    float* bbv = (float*)carve((size_t)9 * DD * 4);

    float* out = (float*)d_out;
    const int tileBlk = NP / 128;        // 1172
    const int pgBlk = (NG * DD) / 256;   // 4096

    // ---- prep (weights pack + BN fold) ----
    prep_w_kernel<<<72, 256, 0, stream>>>(initW, W1, W2, Wph, Wpl);
    prep_scb_kernel<<<5, 256, 0, stream>>>(initb, b1, g1, be1, rm1, rv1,
                                           b2, g2, be2, rm2, rv2, scv, bbv);

    // ---- CSR build (once, reused across 4 layers) ----
    zero_int_kernel<<<586, 256, 0, stream>>>(deg, NN);
    hist_kernel<<<2344, 256, 0, stream>>>(dstArr, deg);
    scan_reduce_kernel<<<NB_SCAN, 256, 0, stream>>>(deg, bsum);
    scan_mid_kernel<<<1, 256, 0, stream>>>(bsum, boff, rowptr + NN);
    scan_final_kernel<<<NB_SCAN, 256, 0, stream>>>(deg, boff, rowptr);
    copy_int_kernel<<<586, 256, 0, stream>>>(rowptr, cursor, NN);
    fill_kernel<<<2344, 256, 0, stream>>>(srcArr, dstArr, cursor, csr_src);

    // ---- fused encoder + init GEMM + init pool ----
    fillpat_kernel<<<pgBlk, 256, 0, stream>>>((unsigned*)P, ENC_NEG_INF, NG * DD);
    init_fused_kernel<<<tileBlk, 256, 0, stream>>>(x, encW, encb, batch, Wph, Wpl,
                                                   scv, bbv, A, (unsigned*)P);
    decode_kernel<<<pgBlk, 256, 0, stream>>>((const unsigned*)P, OUTb);

    float* pin = A;
    float* pout = B;
    for (int i = 0; i < NL; i++) {
        fillpat_kernel<<<pgBlk, 256, 0, stream>>>((unsigned*)P, 0u, NG * DD);
        // B = (1+eps)*A + CSR-sum(A)
        agg_kernel<<<NN / 8, 256, 0, stream>>>((const f32x4*)pin, rowptr, csr_src,
                                               gin_eps, i, (f32x4*)pout);
        // pin_next = relu(bn2( relu(bn1(pout@W1)) @ W2 )) ; P = pool
        mm2xp_kernel<<<tileBlk, 256, 0, stream>>>(
            pout, pin, batch,
            Wph + (size_t)(1 + i) * 2048, Wpl + (size_t)(1 + i) * 2048,
            Wph + (size_t)(5 + i) * 2048, Wpl + (size_t)(5 + i) * 2048,
            scv + (1 + i) * DD, bbv + (1 + i) * DD,
            scv + (5 + i) * DD, bbv + (5 + i) * DD, P);
        // OUT += P @ linW + linb
        linacc_kernel<<<NG / 4, DD, 0, stream>>>(P, linW + (size_t)i * DD * DD,
                                                 linb + i * DD, OUTb);
        // note: pin/pout swap is implicit — agg reads pin, mm2xp writes back into pin;
        // pout only holds the aggregated tile. pin stays the activation buffer.
    }

    post_kernel<<<NG, DD, 0, stream>>>(OUTb, postW1, postb1, postW2, postb2, S);
    pred_kernel<<<(NEL + 255) / 256, 256, 0, stream>>>(eil, el, S, out);
}

// Round 10
// 1016.146 us; speedup vs baseline: 1.5908x; 1.2649x over previous
//
#include <hip/hip_runtime.h>

#define NN 150000
#define NP 150016   // NN padded to multiple of 128
#define NE 600000
#define NG 8192
#define DD 128
#define FINN 16
#define NL 4
#define NEL 500000
#define BN_EPS 1e-5f
#define NB_SCAN 147  // ceil(NN/1024)

typedef __attribute__((ext_vector_type(8))) short bf16x8;
typedef __attribute__((ext_vector_type(4))) float f32x4;
typedef __attribute__((ext_vector_type(2))) float f32x2;

__device__ inline short bfr(float x) {
    unsigned u = __builtin_bit_cast(unsigned, x);
    unsigned r = u + 0x7fffu + ((u >> 16) & 1u);
    return (short)(r >> 16);
}
__device__ inline float bf2f(short h) {
    return __builtin_bit_cast(float, ((unsigned)(unsigned short)h) << 16);
}

// ---------------- encoder: A[n][d] = x[n][:16] @ encW + encb ----------------
__global__ __launch_bounds__(256) void enc_kernel(const float* __restrict__ x,
                                                  const float* __restrict__ W,
                                                  const float* __restrict__ b,
                                                  float* __restrict__ out) {
    int t = threadIdx.x;
    int c4 = (t & 31) * 4;
    float4 wreg[16];
#pragma unroll
    for (int k = 0; k < 16; k++) wreg[k] = *(const float4*)&W[k * DD + c4];
    float4 bias = *(const float4*)&b[c4];
    int rbase = blockIdx.x * 128 + (t >> 5);
#pragma unroll
    for (int it = 0; it < 16; it++) {
        int row = rbase + it * 8;
        if (row >= NN) break;
        const float4* xr = (const float4*)(x + (size_t)row * FINN);
        float4 x0 = xr[0], x1 = xr[1], x2 = xr[2], x3 = xr[3];
        float xs[16] = {x0.x, x0.y, x0.z, x0.w, x1.x, x1.y, x1.z, x1.w,
                        x2.x, x2.y, x2.z, x2.w, x3.x, x3.y, x3.z, x3.w};
        float4 acc = bias;
#pragma unroll
        for (int k = 0; k < 16; k++) {
            acc.x += xs[k] * wreg[k].x;
            acc.y += xs[k] * wreg[k].y;
            acc.z += xs[k] * wreg[k].z;
            acc.w += xs[k] * wreg[k].w;
        }
        *(float4*)&out[(size_t)row * DD + c4] = acc;
    }
}

// ------- pack 9 weight matrices into MFMA B-fragment layout, hi+lo split -------
__global__ void prep_w_kernel(const float* __restrict__ initW, const float* __restrict__ W1,
                              const float* __restrict__ W2, bf16x8* __restrict__ Wph,
                              bf16x8* __restrict__ Wpl) {
    int tid = blockIdx.x * 256 + threadIdx.x;  // 9*2048 = 18432
    if (tid >= 9 * 2048) return;
    int mat = tid >> 11;
    int rem = tid & 2047;
    int kk = rem >> 9;
    int c = (rem >> 6) & 7;
    int lane = rem & 63;
    const float* Wm;
    if (mat == 0) Wm = initW;
    else if (mat <= 4) Wm = W1 + (size_t)(mat - 1) * DD * DD;
    else Wm = W2 + (size_t)(mat - 5) * DD * DD;
    int col = c * 16 + (lane & 15);
    int kbase = kk * 32 + (lane >> 4) * 8;
    bf16x8 oh, ol;
#pragma unroll
    for (int j = 0; j < 8; j++) {
        float v = Wm[(size_t)(kbase + j) * DD + col];
        short h = bfr(v);
        oh[j] = h;
        ol[j] = bfr(v - bf2f(h));
    }
    Wph[tid] = oh;
    Wpl[tid] = ol;
}

// ---------------- fold BN into per-column scale/bias ----------------
__global__ void prep_scb_kernel(const float* __restrict__ initb,
                                const float* __restrict__ b1, const float* __restrict__ g1,
                                const float* __restrict__ be1, const float* __restrict__ rm1,
                                const float* __restrict__ rv1,
                                const float* __restrict__ b2, const float* __restrict__ g2,
                                const float* __restrict__ be2, const float* __restrict__ rm2,
                                const float* __restrict__ rv2,
                                float* __restrict__ sc, float* __restrict__ bb) {
    int tid = blockIdx.x * 256 + threadIdx.x;  // 9*128
    if (tid >= 9 * DD) return;
    int mat = tid >> 7, d = tid & 127;
    float s, o;
    if (mat == 0) {
        s = 1.f;
        o = initb[d];
    } else {
        const float *b_, *g_, *be_, *rm_, *rv_;
        int i;
        if (mat <= 4) { i = mat - 1; b_ = b1; g_ = g1; be_ = be1; rm_ = rm1; rv_ = rv1; }
        else          { i = mat - 5; b_ = b2; g_ = g2; be_ = be2; rm_ = rm2; rv_ = rv2; }
        float t = g_[i * DD + d] * rsqrtf(rv_[i * DD + d] + BN_EPS);
        s = t;
        o = (b_[i * DD + d] - rm_[i * DD + d]) * t + be_[i * DD + d];
    }
    sc[tid] = s;
    bb[tid] = o;
}

// ---------------- CSR build ----------------
__global__ void zero_int_kernel(int* __restrict__ p, int n) {
    int i = blockIdx.x * 256 + threadIdx.x;
    if (i < n) p[i] = 0;
}

__global__ void hist_kernel(const int* __restrict__ dst, int* __restrict__ deg) {
    int e = blockIdx.x * 256 + threadIdx.x;
    if (e < NE) atomicAdd(&deg[dst[e]], 1);
}

__global__ void scan_reduce_kernel(const int* __restrict__ deg, int* __restrict__ bsum) {
    __shared__ int s[256];
    int b = blockIdx.x, t = threadIdx.x;
    int base = b * 1024 + t * 4;
    int v = 0;
#pragma unroll
    for (int i = 0; i < 4; i++) {
        int idx = base + i;
        if (idx < NN) v += deg[idx];
    }
    s[t] = v;
    __syncthreads();
    for (int off = 128; off > 0; off >>= 1) {
        if (t < off) s[t] += s[t + off];
        __syncthreads();
    }
    if (t == 0) bsum[b] = s[0];
}

__global__ void scan_mid_kernel(const int* __restrict__ bsum, int* __restrict__ boff,
                                int* __restrict__ rowptrN) {
    __shared__ int s[256];
    int t = threadIdx.x;
    int v = (t < NB_SCAN) ? bsum[t] : 0;
    s[t] = v;
    __syncthreads();
    for (int off = 1; off < 256; off <<= 1) {
        int u = (t >= off) ? s[t - off] : 0;
        __syncthreads();
        s[t] += u;
        __syncthreads();
    }
    if (t < NB_SCAN) boff[t] = s[t] - v;
    if (t == 255) *rowptrN = s[255];
}

__global__ void scan_final_kernel(const int* __restrict__ deg, const int* __restrict__ boff,
                                  int* __restrict__ rowptr) {
    __shared__ int s[256];
    int b = blockIdx.x, t = threadIdx.x;
    int base = b * 1024 + t * 4;
    int v[4];
    int sum = 0;
#pragma unroll
    for (int i = 0; i < 4; i++) {
        int idx = base + i;
        v[i] = (idx < NN) ? deg[idx] : 0;
        sum += v[i];
    }
    s[t] = sum;
    __syncthreads();
    int my = sum;
    for (int off = 1; off < 256; off <<= 1) {
        int u = (t >= off) ? s[t - off] : 0;
        __syncthreads();
        s[t] += u;
        __syncthreads();
    }
    int excl = s[t] - my + boff[b];
#pragma unroll
    for (int i = 0; i < 4; i++) {
        int idx = base + i;
        if (idx < NN) rowptr[idx] = excl;
        excl += v[i];
    }
}

__global__ void copy_int_kernel(const int* __restrict__ a, int* __restrict__ b, int n) {
    int i = blockIdx.x * 256 + threadIdx.x;
    if (i < n) b[i] = a[i];
}

__global__ void fill_kernel(const int* __restrict__ src, const int* __restrict__ dst,
                            int* cursor, int* __restrict__ csr_src) {
    int e = blockIdx.x * 256 + threadIdx.x;
    if (e >= NE) return;
    int p = atomicAdd(&cursor[dst[e]], 1);
    csr_src[p] = src[e];
}

// ---------------- graph segment starts (batch sorted) ----------------
__global__ void gstart_kernel(const int* __restrict__ batch, int* __restrict__ gstart) {
    int n = blockIdx.x * 256 + threadIdx.x;
    if (n >= NN) return;
    int b = batch[n];
    int prev = (n == 0) ? -1 : batch[n - 1];
    for (int g = prev + 1; g <= b; g++) gstart[g] = n;
    if (n == NN - 1) {
        for (int g = b + 1; g <= NG; g++) gstart[g] = NN;
    }
}

// ------- fused GIN aggregation: B[n] = (1+eps)*A[n] + sum_{j in N(n)} A[j] -------
// ONE ROW PER WAVE: 64 lanes x f32x2 = full 512B row per instruction.
// Row index / extents / neighbor indices hoisted to SGPRs via readfirstlane ->
// gathers use SGPR-base + lane-offset; 8 independent gathers per batch.
__global__ __launch_bounds__(256) void agg_kernel(const float* __restrict__ A,
                                                  const int* __restrict__ rowptr,
                                                  const int* __restrict__ csr_src,
                                                  const float* __restrict__ gin_eps,
                                                  int li, float* __restrict__ B) {
    int n = __builtin_amdgcn_readfirstlane(blockIdx.x * 4 + (threadIdx.x >> 6));
    int c2 = (threadIdx.x & 63) * 2;
    float e1 = 1.f + gin_eps[li];
    int s = __builtin_amdgcn_readfirstlane(rowptr[n]);
    int e = __builtin_amdgcn_readfirstlane(rowptr[n + 1]);
    f32x2 acc = *(const f32x2*)&A[(size_t)n * DD + c2] * e1;
    int i = s;
    for (; i + 8 <= e; i += 8) {
        int j0 = __builtin_amdgcn_readfirstlane(csr_src[i + 0]);
        int j1 = __builtin_amdgcn_readfirstlane(csr_src[i + 1]);
        int j2 = __builtin_amdgcn_readfirstlane(csr_src[i + 2]);
        int j3 = __builtin_amdgcn_readfirstlane(csr_src[i + 3]);
        int j4 = __builtin_amdgcn_readfirstlane(csr_src[i + 4]);
        int j5 = __builtin_amdgcn_readfirstlane(csr_src[i + 5]);
        int j6 = __builtin_amdgcn_readfirstlane(csr_src[i + 6]);
        int j7 = __builtin_amdgcn_readfirstlane(csr_src[i + 7]);
        f32x2 v0 = *(const f32x2*)&A[(size_t)j0 * DD + c2];
        f32x2 v1 = *(const f32x2*)&A[(size_t)j1 * DD + c2];
        f32x2 v2 = *(const f32x2*)&A[(size_t)j2 * DD + c2];
        f32x2 v3 = *(const f32x2*)&A[(size_t)j3 * DD + c2];
        f32x2 v4 = *(const f32x2*)&A[(size_t)j4 * DD + c2];
        f32x2 v5 = *(const f32x2*)&A[(size_t)j5 * DD + c2];
        f32x2 v6 = *(const f32x2*)&A[(size_t)j6 * DD + c2];
        f32x2 v7 = *(const f32x2*)&A[(size_t)j7 * DD + c2];
        acc += ((v0 + v1) + (v2 + v3)) + ((v4 + v5) + (v6 + v7));
    }
    if (i + 4 <= e) {
        int j0 = __builtin_amdgcn_readfirstlane(csr_src[i + 0]);
        int j1 = __builtin_amdgcn_readfirstlane(csr_src[i + 1]);
        int j2 = __builtin_amdgcn_readfirstlane(csr_src[i + 2]);
        int j3 = __builtin_amdgcn_readfirstlane(csr_src[i + 3]);
        f32x2 v0 = *(const f32x2*)&A[(size_t)j0 * DD + c2];
        f32x2 v1 = *(const f32x2*)&A[(size_t)j1 * DD + c2];
        f32x2 v2 = *(const f32x2*)&A[(size_t)j2 * DD + c2];
        f32x2 v3 = *(const f32x2*)&A[(size_t)j3 * DD + c2];
        acc += (v0 + v1) + (v2 + v3);
        i += 4;
    }
    for (; i < e; i++) {
        int j = __builtin_amdgcn_readfirstlane(csr_src[i]);
        acc += *(const f32x2*)&A[(size_t)j * DD + c2];
    }
    *(f32x2*)&B[(size_t)n * DD + c2] = acc;
}

// ------- split-bf16 MFMA GEMM: C = act(sc*(A@W) + bb), A fp32 [NP,128] -------
template <int RELU>
__global__ __launch_bounds__(256) void mm_kernel(const float* __restrict__ A,
                                                 float* __restrict__ C,
                                                 const bf16x8* __restrict__ Wph,
                                                 const bf16x8* __restrict__ Wpl,
                                                 const float* __restrict__ sc,
                                                 const float* __restrict__ bb) {
    int lane = threadIdx.x & 63;
    int wid = threadIdx.x >> 6;
    int row0 = blockIdx.x * 128 + wid * 32;
    int r16 = lane & 15;
    int kg = lane >> 4;
    f32x4 acc[2][8];
#pragma unroll
    for (int m = 0; m < 2; m++)
#pragma unroll
        for (int c = 0; c < 8; c++) acc[m][c] = (f32x4){0.f, 0.f, 0.f, 0.f};
#pragma unroll
    for (int kk = 0; kk < 4; kk++) {
        bf16x8 ah[2], al[2];
#pragma unroll
        for (int m = 0; m < 2; m++) {
            const float* ap = A + (size_t)(row0 + m * 16 + r16) * DD + kk * 32 + kg * 8;
            float4 lo = *(const float4*)ap;
            float4 hi = *(const float4*)(ap + 4);
            float v[8] = {lo.x, lo.y, lo.z, lo.w, hi.x, hi.y, hi.z, hi.w};
            bf16x8 th, tl;
#pragma unroll
            for (int j = 0; j < 8; j++) {
                short h = bfr(v[j]);
                th[j] = h;
                tl[j] = bfr(v[j] - bf2f(h));
            }
            ah[m] = th;
            al[m] = tl;
        }
#pragma unroll
        for (int c = 0; c < 8; c++) {
            bf16x8 wh = Wph[kk * 512 + c * 64 + lane];
            bf16x8 wl = Wpl[kk * 512 + c * 64 + lane];
#pragma unroll
            for (int m = 0; m < 2; m++) {
                acc[m][c] = __builtin_amdgcn_mfma_f32_16x16x32_bf16(ah[m], wh, acc[m][c], 0, 0, 0);
                acc[m][c] = __builtin_amdgcn_mfma_f32_16x16x32_bf16(al[m], wh, acc[m][c], 0, 0, 0);
                acc[m][c] = __builtin_amdgcn_mfma_f32_16x16x32_bf16(ah[m], wl, acc[m][c], 0, 0, 0);
            }
        }
    }
#pragma unroll
    for (int c = 0; c < 8; c++) {
        int col = c * 16 + r16;
        float s = sc[col], o = bb[col];
#pragma unroll
        for (int m = 0; m < 2; m++) {
            int rbase = row0 + m * 16 + kg * 4;
#pragma unroll
            for (int j = 0; j < 4; j++) {
                int row = rbase + j;
                if (row < NN) {
                    float v = acc[m][c][j] * s + o;
                    if (RELU) v = fmaxf(v, 0.f);
                    C[(size_t)row * DD + col] = v;
                }
            }
        }
    }
}

// ------- fused double GEMM: Aout = relu(bn2( relu(bn1(Ain@W1)) @ W2 ))  -------
// h tile (128x128 fp32) lives in XOR-swizzled LDS; no global h round-trip.
__global__ __launch_bounds__(256) void mm2x_kernel(
    const float* __restrict__ Ain, float* __restrict__ Aout,
    const bf16x8* __restrict__ Wph1, const bf16x8* __restrict__ Wpl1,
    const bf16x8* __restrict__ Wph2, const bf16x8* __restrict__ Wpl2,
    const float* __restrict__ sc1, const float* __restrict__ bb1,
    const float* __restrict__ sc2, const float* __restrict__ bb2) {
    __shared__ float hl[128 * 128];  // phys col = logical col ^ ((row&7)<<2)
    int lane = threadIdx.x & 63;
    int wid = threadIdx.x >> 6;
    int row0 = blockIdx.x * 128 + wid * 32;
    int r16 = lane & 15;
    int kg = lane >> 4;
    f32x4 acc[2][8];
#pragma unroll
    for (int m = 0; m < 2; m++)
#pragma unroll
        for (int c = 0; c < 8; c++) acc[m][c] = (f32x4){0.f, 0.f, 0.f, 0.f};

    // ---- GEMM1: Ain @ W1 ----
#pragma unroll
    for (int kk = 0; kk < 4; kk++) {
        bf16x8 ah[2], al[2];
#pragma unroll
        for (int m = 0; m < 2; m++) {
            const float* ap = Ain + (size_t)(row0 + m * 16 + r16) * DD + kk * 32 + kg * 8;
            float4 lo = *(const float4*)ap;
            float4 hi = *(const float4*)(ap + 4);
            float v[8] = {lo.x, lo.y, lo.z, lo.w, hi.x, hi.y, hi.z, hi.w};
            bf16x8 th, tl;
#pragma unroll
            for (int j = 0; j < 8; j++) {
                short h = bfr(v[j]);
                th[j] = h;
                tl[j] = bfr(v[j] - bf2f(h));
            }
            ah[m] = th;
            al[m] = tl;
        }
#pragma unroll
        for (int c = 0; c < 8; c++) {
            bf16x8 wh = Wph1[kk * 512 + c * 64 + lane];
            bf16x8 wl = Wpl1[kk * 512 + c * 64 + lane];
#pragma unroll
            for (int m = 0; m < 2; m++) {
                acc[m][c] = __builtin_amdgcn_mfma_f32_16x16x32_bf16(ah[m], wh, acc[m][c], 0, 0, 0);
                acc[m][c] = __builtin_amdgcn_mfma_f32_16x16x32_bf16(al[m], wh, acc[m][c], 0, 0, 0);
                acc[m][c] = __builtin_amdgcn_mfma_f32_16x16x32_bf16(ah[m], wl, acc[m][c], 0, 0, 0);
            }
        }
    }
    // ---- epilogue1: relu(bn1) -> swizzled LDS ----
#pragma unroll
    for (int c = 0; c < 8; c++) {
        int col = c * 16 + r16;
        float s = sc1[col], o = bb1[col];
#pragma unroll
        for (int m = 0; m < 2; m++) {
#pragma unroll
            for (int j = 0; j < 4; j++) {
                int rl = wid * 32 + m * 16 + kg * 4 + j;
                float v = fmaxf(acc[m][c][j] * s + o, 0.f);
                hl[rl * 128 + (col ^ ((rl & 7) << 2))] = v;
            }
        }
    }
    __syncthreads();

    // ---- GEMM2: h @ W2 ----
#pragma unroll
    for (int m = 0; m < 2; m++)
#pragma unroll
        for (int c = 0; c < 8; c++) acc[m][c] = (f32x4){0.f, 0.f, 0.f, 0.f};
#pragma unroll
    for (int kk = 0; kk < 4; kk++) {
        bf16x8 ah[2], al[2];
#pragma unroll
        for (int m = 0; m < 2; m++) {
            int rl = wid * 32 + m * 16 + r16;
            int sw = (rl & 7) << 2;
            int c0 = kk * 32 + kg * 8;
            float4 lo = *(const float4*)&hl[rl * 128 + (c0 ^ sw)];
            float4 hi = *(const float4*)&hl[rl * 128 + ((c0 + 4) ^ sw)];
            float v[8] = {lo.x, lo.y, lo.z, lo.w, hi.x, hi.y, hi.z, hi.w};
            bf16x8 th, tl;
#pragma unroll
            for (int j = 0; j < 8; j++) {
                short h = bfr(v[j]);
                th[j] = h;
                tl[j] = bfr(v[j] - bf2f(h));
            }
            ah[m] = th;
            al[m] = tl;
        }
#pragma unroll
        for (int c = 0; c < 8; c++) {
            bf16x8 wh = Wph2[kk * 512 + c * 64 + lane];
            bf16x8 wl = Wpl2[kk * 512 + c * 64 + lane];
#pragma unroll
            for (int m = 0; m < 2; m++) {
                acc[m][c] = __builtin_amdgcn_mfma_f32_16x16x32_bf16(ah[m], wh, acc[m][c], 0, 0, 0);
                acc[m][c] = __builtin_amdgcn_mfma_f32_16x16x32_bf16(al[m], wh, acc[m][c], 0, 0, 0);
                acc[m][c] = __builtin_amdgcn_mfma_f32_16x16x32_bf16(ah[m], wl, acc[m][c], 0, 0, 0);
            }
        }
    }
    // ---- epilogue2: relu(bn2) -> global ----
#pragma unroll
    for (int c = 0; c < 8; c++) {
        int col = c * 16 + r16;
        float s = sc2[col], o = bb2[col];
#pragma unroll
        for (int m = 0; m < 2; m++) {
            int rbase = row0 + m * 16 + kg * 4;
#pragma unroll
            for (int j = 0; j < 4; j++) {
                int row = rbase + j;
                if (row < NN) {
                    Aout[(size_t)row * DD + col] = fmaxf(acc[m][c][j] * s + o, 0.f);
                }
            }
        }
    }
}

// ---------------- pool (range-based) -> OUT[g][d] = max ----------------
__global__ void pool0_kernel(const float* __restrict__ X, const int* __restrict__ gstart,
                             float* __restrict__ OUT) {
    int gph = blockIdx.x;
    int d = threadIdx.x;  // 128
    int start = gstart[gph], end = gstart[gph + 1];
    float m;
    if (start >= end) {
        m = 0.f;
    } else {
        m = -INFINITY;
        for (int n = start; n < end; n++) m = fmaxf(m, X[(size_t)n * DD + d]);
    }
    OUT[(size_t)gph * DD + d] = m;
}

// ------- fused pool + linear-accumulate: OUT[g] += max_pool(X,g) @ W + b -------
__global__ __launch_bounds__(128) void poollin_kernel(const float* __restrict__ X,
                                                      const int* __restrict__ gstart,
                                                      const float* __restrict__ W,
                                                      const float* __restrict__ b,
                                                      float* __restrict__ OUT) {
    __shared__ float p[4][DD];
    int g0 = blockIdx.x * 4;
    int d = threadIdx.x;
#pragma unroll
    for (int gg = 0; gg < 4; gg++) {
        int start = gstart[g0 + gg], end = gstart[g0 + gg + 1];
        float m;
        if (start >= end) {
            m = 0.f;
        } else {
            m = -INFINITY;
            for (int n = start; n < end; n++) m = fmaxf(m, X[(size_t)n * DD + d]);
        }
        p[gg][d] = m;
    }
    __syncthreads();
    float acc0 = b[d], acc1 = b[d], acc2 = b[d], acc3 = b[d];
#pragma unroll 8
    for (int k = 0; k < DD; k++) {
        float w = W[k * DD + d];
        acc0 += p[0][k] * w;
        acc1 += p[1][k] * w;
        acc2 += p[2][k] * w;
        acc3 += p[3][k] * w;
    }
    OUT[(size_t)(g0 + 0) * DD + d] += acc0;
    OUT[(size_t)(g0 + 1) * DD + d] += acc1;
    OUT[(size_t)(g0 + 2) * DD + d] += acc2;
    OUT[(size_t)(g0 + 3) * DD + d] += acc3;
}

// ---------------- post MLP -> scalar per graph ----------------
__global__ void post_kernel(const float* __restrict__ OUT, const float* __restrict__ W1,
                            const float* __restrict__ b1, const float* __restrict__ W2,
                            const float* __restrict__ b2, float* __restrict__ S) {
    __shared__ float o[DD];
    __shared__ float red[2];
    int gph = blockIdx.x, d = threadIdx.x;
    o[d] = fmaxf(OUT[(size_t)gph * DD + d], 0.f);
    __syncthreads();
    float acc = b1[d];
#pragma unroll 8
    for (int k = 0; k < DD; k++) acc += o[k] * W1[k * DD + d];
    acc = fmaxf(acc, 0.f);
    float v = acc * W2[d];
#pragma unroll
    for (int off = 32; off > 0; off >>= 1) v += __shfl_down(v, off);
    if ((d & 63) == 0) red[d >> 6] = v;
    __syncthreads();
    if (d == 0) S[gph] = red[0] + red[1] + b2[0];
}

// ---------------- decode ----------------
__global__ void pred_kernel(const int* __restrict__ eil, const int* __restrict__ el,
                            const float* __restrict__ S, float* __restrict__ out) {
    int i = blockIdx.x * blockDim.x + threadIdx.x;
    if (i >= NEL) return;
    int a = eil[i], b = eil[NEL + i];
    out[i] = S[a] * S[b];
    out[NEL + i] = (float)el[i];
}

extern "C" void kernel_launch(void* const* d_in, const int* in_sizes, int n_in,
                              void* d_out, int out_size, void* d_ws, size_t ws_size,
                              hipStream_t stream) {
    const float* x = (const float*)d_in[0];
    const int* edge_index = (const int*)d_in[1];
    const int* batch = (const int*)d_in[2];
    const int* eil = (const int*)d_in[3];
    const int* el = (const int*)d_in[4];
    const float* encW = (const float*)d_in[5];
    const float* encb = (const float*)d_in[6];
    const float* initW = (const float*)d_in[7];
    const float* initb = (const float*)d_in[8];
    const float* gin_eps = (const float*)d_in[9];
    const float* W1 = (const float*)d_in[10];
    const float* b1 = (const float*)d_in[11];
    const float* g1 = (const float*)d_in[12];
    const float* be1 = (const float*)d_in[13];
    const float* rm1 = (const float*)d_in[14];
    const float* rv1 = (const float*)d_in[15];
    const float* W2 = (const float*)d_in[16];
    const float* b2 = (const float*)d_in[17];
    const float* g2 = (const float*)d_in[18];
    const float* be2 = (const float*)d_in[19];
    const float* rm2 = (const float*)d_in[20];
    const float* rv2 = (const float*)d_in[21];
    const float* linW = (const float*)d_in[22];
    const float* linb = (const float*)d_in[23];
    const float* postW1 = (const float*)d_in[24];
    const float* postb1 = (const float*)d_in[25];
    const float* postW2 = (const float*)d_in[26];
    const float* postb2 = (const float*)d_in[27];

    const int* srcArr = edge_index;
    const int* dstArr = edge_index + NE;

    // workspace carve (256B aligned)
    char* w = (char*)d_ws;
    auto carve = [&](size_t bytes) -> char* {
        char* p = w;
        w += (bytes + 255) & ~(size_t)255;
        return p;
    };
    float* A = (float*)carve((size_t)NP * DD * 4);
    float* B = (float*)carve((size_t)NP * DD * 4);
    float* OUTb = (float*)carve((size_t)NG * DD * 4);
    float* S = (float*)carve((size_t)NG * 4);
    int* deg = (int*)carve((size_t)NN * 4);
    int* rowptr = (int*)carve((size_t)(NN + 1) * 4);
    int* cursor = (int*)carve((size_t)NN * 4);
    int* csr_src = (int*)carve((size_t)NE * 4);
    int* bsum = (int*)carve((size_t)NB_SCAN * 4);
    int* boff = (int*)carve((size_t)NB_SCAN * 4);
    int* gstart = (int*)carve((size_t)(NG + 1) * 4);
    bf16x8* Wph = (bf16x8*)carve((size_t)9 * 2048 * 16);
    bf16x8* Wpl = (bf16x8*)carve((size_t)9 * 2048 * 16);
    float* scv = (float*)carve((size_t)9 * DD * 4);
    float* bbv = (float*)carve((size_t)9 * DD * 4);

    float* out = (float*)d_out;
    const int mmBlk = NP / 128;  // 1172

    // ---- prep (weights pack + BN fold) ----
    prep_w_kernel<<<72, 256, 0, stream>>>(initW, W1, W2, Wph, Wpl);
    prep_scb_kernel<<<5, 256, 0, stream>>>(initb, b1, g1, be1, rm1, rv1,
                                           b2, g2, be2, rm2, rv2, scv, bbv);

    // ---- CSR build (once, reused across 4 layers) ----
    zero_int_kernel<<<586, 256, 0, stream>>>(deg, NN);
    hist_kernel<<<2344, 256, 0, stream>>>(dstArr, deg);
    scan_reduce_kernel<<<NB_SCAN, 256, 0, stream>>>(deg, bsum);
    scan_mid_kernel<<<1, 256, 0, stream>>>(bsum, boff, rowptr + NN);
    scan_final_kernel<<<NB_SCAN, 256, 0, stream>>>(deg, boff, rowptr);
    copy_int_kernel<<<586, 256, 0, stream>>>(rowptr, cursor, NN);
    fill_kernel<<<2344, 256, 0, stream>>>(srcArr, dstArr, cursor, csr_src);
    gstart_kernel<<<586, 256, 0, stream>>>(batch, gstart);

    // ---- encoder -> A ----
    enc_kernel<<<mmBlk, 256, 0, stream>>>(x, encW, encb, A);
    // B = A @ initW + initb   (mat 0, no relu)
    mm_kernel<0><<<mmBlk, 256, 0, stream>>>(A, B, Wph, Wpl, scv, bbv);
    // OUT = pool(B)
    pool0_kernel<<<NG, DD, 0, stream>>>(B, gstart, OUTb);

    for (int i = 0; i < NL; i++) {
        // B = (1+eps)*A + CSR-sum(A)   (one row per wave)
        agg_kernel<<<NN / 4, 256, 0, stream>>>(A, rowptr, csr_src, gin_eps, i, B);
        // A = relu(bn2( relu(bn1(B@W1)) @ W2 ))  — fused, h in LDS
        mm2x_kernel<<<mmBlk, 256, 0, stream>>>(
            B, A,
            Wph + (size_t)(1 + i) * 2048, Wpl + (size_t)(1 + i) * 2048,
            Wph + (size_t)(5 + i) * 2048, Wpl + (size_t)(5 + i) * 2048,
            scv + (1 + i) * DD, bbv + (1 + i) * DD,
            scv + (5 + i) * DD, bbv + (5 + i) * DD);
        // OUT += pool(A) @ linW + linb
        poollin_kernel<<<NG / 4, DD, 0, stream>>>(A, gstart, linW + (size_t)i * DD * DD,
                                                  linb + i * DD, OUTb);
    }

    post_kernel<<<NG, DD, 0, stream>>>(OUTb, postW1, postb1, postW2, postb2, S);
    pred_kernel<<<(NEL + 255) / 256, 256, 0, stream>>>(eil, el, S, out);
}